// Round 2
// baseline (2052.040 us; speedup 1.0000x reference)
//
#include <hip/hip_runtime.h>

// bf16 pack/unpack for LDS-resident intermediates (global I/O is fp32)
__device__ __forceinline__ unsigned short f2bf(float f) {
    unsigned int u = __float_as_uint(f);
    u += 0x7fffu + ((u >> 16) & 1u);   // RNE
    return (unsigned short)(u >> 16);
}
__device__ __forceinline__ float bfs(const unsigned short* p) {
    return __uint_as_float(((unsigned int)*p) << 16);
}
__device__ __forceinline__ float dot4(float4 w, const float* xv, float a) {
    a = fmaf(w.x, xv[0], a);
    a = fmaf(w.y, xv[1], a);
    a = fmaf(w.z, xv[2], a);
    a = fmaf(w.w, xv[3], a);
    return a;
}

// One block per 8x8 window (4096 windows), 256 threads = 4 waves.
// Fused: qkv 1x1 -> dw3x3 -> L2norm -> ch-attn + sp-attn(+bias) -> proj.
__global__ __launch_bounds__(256, 2)
void fused_win_attn(const float* __restrict__ x,
                    const float* __restrict__ qkv_w,
                    const float* __restrict__ qkv_b,
                    const float* __restrict__ dw_w,
                    const float* __restrict__ dw_b,
                    const float* __restrict__ proj_w,
                    const float* __restrict__ proj_b,
                    const float* __restrict__ temperature,
                    const float* __restrict__ rel_bias,
                    float* __restrict__ yout)
{
    // LDS: 24576 + 12480 + 12672 + 13696 = 63424 B (<64KB -> 2 blocks/CU)
    __shared__ __align__(16) float s_x[96][64];           // input window fp32
    __shared__ float s_post[48][65];                      // q|k|v after dwconv (head-local)
    __shared__ unsigned short s_out[96][66];              // pre-proj out, bf16
    __shared__ __align__(16) unsigned char s_un[13696];   // time-multiplexed
    float*          s_pre = (float*)s_un;                  // [48][65] pre-dwconv qkv
    unsigned short* s_sp  = (unsigned short*)s_un;         // [64][66] attn_sp (bf16)
    float*          s_ch  = (float*)(s_un + 8448);         // [16][17] attn_ch
    float*          s_tmp = (float*)(s_un + 9536);         // [16][65] attn_ch @ v

    const int tid  = threadIdx.x;
    const int lane = tid & 63;        // pixel p = py*8+px
    const int g    = tid >> 6;        // wave 0..3
    const int wi   = blockIdx.x;
    const int y0   = (wi >> 6) << 3;
    const int x0   = (wi & 63) << 3;
    const int py   = lane >> 3, px = lane & 7;

    // ---- stage input window (96ch x 8 x 8), float4 ----
    for (int r = tid; r < 1536; r += 256) {
        const int c = r >> 4, iy = (r >> 1) & 7, half = r & 1;
        *(float4*)&s_x[c][iy * 8 + half * 4] =
            *(const float4*)(x + c * 262144 + (y0 + iy) * 512 + x0 + half * 4);
    }
    __syncthreads();

    float pacc[24];   // proj accumulators live across the head loop? no: init later
    (void)pacc;

    for (int h = 0; h < 6; ++h) {
        // ---- qkv 1x1: 48 rows (q|k|v of head h) x 64 px, K=96; row j -> wave j&3 ----
        float acc[12];
        const float* wrow[12];
        #pragma unroll
        for (int r = 0; r < 12; ++r) {
            const int j = g + 4 * r;
            const int O = (j >> 4) * 96 + h * 16 + (j & 15);
            wrow[r] = qkv_w + O * 96;
            acc[r]  = qkv_b[O];
        }
        for (int i0 = 0; i0 < 96; i0 += 4) {
            float xv[4];
            #pragma unroll
            for (int u = 0; u < 4; ++u) xv[u] = s_x[i0 + u][lane];
            #pragma unroll
            for (int r = 0; r < 12; ++r)
                acc[r] = dot4(*(const float4*)(wrow[r] + i0), xv, acc[r]);
        }
        #pragma unroll
        for (int r = 0; r < 12; ++r) s_pre[(g + 4 * r) * 65 + lane] = acc[r];

        // ---- depthwise 3x3, zero-padded within the window (wave-private rows) ----
        #pragma unroll
        for (int r = 0; r < 12; ++r) {
            const int j = g + 4 * r;
            const int O = (j >> 4) * 96 + h * 16 + (j & 15);
            const float* dwr = dw_w + O * 9;
            const float* pre = s_pre + j * 65;
            float s = dw_b[O];
            #pragma unroll
            for (int di = 0; di < 3; ++di) {
                const int yy = py + di - 1;
                #pragma unroll
                for (int dj = 0; dj < 3; ++dj) {
                    const int xx = px + dj - 1;
                    const bool ok = ((unsigned)yy < 8u) & ((unsigned)xx < 8u);
                    const float v = ok ? pre[yy * 8 + xx] : 0.f;
                    s = fmaf(dwr[di * 3 + dj], v, s);
                }
            }
            s_post[j][lane] = s;
        }

        // ---- L2-normalize q,k rows over N=64 (scale cancels) ----
        #pragma unroll
        for (int r = 0; r < 8; ++r) {
            const int j = g + 4 * r;              // rows 0..31
            const float v = s_post[j][lane];
            float ss = v * v;
            #pragma unroll
            for (int m = 1; m < 64; m <<= 1) ss += __shfl_xor(ss, m, 64);
            s_post[j][lane] = v * (1.f / fmaxf(sqrtf(ss), 1e-12f));
        }
        __syncthreads();

        // ---- channel attention logits (16x16), one per thread ----
        {
            const int cc = tid >> 4, dd = tid & 15;
            float a = 0.f;
            #pragma unroll 8
            for (int n = 0; n < 64; ++n) a += s_post[cc][n] * s_post[16 + dd][n];
            s_ch[cc * 17 + dd] = a * temperature[h];
        }
        __syncthreads();
        if (tid < 16) {
            float mx = -1e30f;
            for (int d = 0; d < 16; ++d) mx = fmaxf(mx, s_ch[tid * 17 + d]);
            float se = 0.f;
            for (int d = 0; d < 16; ++d) {
                const float e = __expf(s_ch[tid * 17 + d] - mx);
                s_ch[tid * 17 + d] = e; se += e;
            }
            const float inv = 1.f / se;
            for (int d = 0; d < 16; ++d) s_ch[tid * 17 + d] *= inv;
        }
        __syncthreads();

        // ---- spatial attn row n per wave; softmax across lanes; bias analytic ----
        for (int r = 0; r < 16; ++r) {
            const int n = 4 * r + g;
            float a = 0.f;
            #pragma unroll
            for (int c = 0; c < 16; ++c) a += s_post[c][n] * s_post[16 + c][lane];
            const int idx = ((n >> 3) - py + 7) * 15 + ((n & 7) - px + 7);
            a += rel_bias[idx * 6 + h];
            float mx = a;
            #pragma unroll
            for (int m = 1; m < 64; m <<= 1) mx = fmaxf(mx, __shfl_xor(mx, m, 64));
            const float e = __expf(a - mx);
            float se = e;
            #pragma unroll
            for (int m = 1; m < 64; m <<= 1) se += __shfl_xor(se, m, 64);
            s_sp[n * 66 + lane] = f2bf(e / se);
        }
        // ---- tmp = attn_ch @ v (16x64) ----
        #pragma unroll
        for (int r = 0; r < 4; ++r) {
            const int c = 4 * r + g;
            float a = 0.f;
            #pragma unroll
            for (int d = 0; d < 16; ++d) a += s_ch[c * 17 + d] * s_post[32 + d][lane];
            s_tmp[c * 65 + lane] = a;
        }
        __syncthreads();
        // ---- out_h = tmp @ attn_sp (16x64), store bf16 ----
        #pragma unroll
        for (int r = 0; r < 4; ++r) {
            const int c = 4 * r + g;
            float a = 0.f;
            #pragma unroll 16
            for (int n = 0; n < 64; ++n)
                a += s_tmp[c * 65 + n] * bfs(s_sp + n * 66 + lane);
            s_out[h * 16 + c][lane] = f2bf(a);
        }
        __syncthreads();   // protect union before next head's s_pre writes
    }

    // ---- proj 1x1 (96 out, K=96) + window reverse + fp32 store ----
    float po[24];
    #pragma unroll
    for (int r = 0; r < 24; ++r) po[r] = proj_b[g + 4 * r];
    for (int i0 = 0; i0 < 96; i0 += 4) {
        float xv[4];
        #pragma unroll
        for (int u = 0; u < 4; ++u) xv[u] = bfs(&s_out[i0 + u][lane]);
        #pragma unroll
        for (int r = 0; r < 24; ++r)
            po[r] = dot4(*(const float4*)(proj_w + (g + 4 * r) * 96 + i0), xv, po[r]);
    }
    #pragma unroll
    for (int r = 0; r < 24; ++r) {
        const int o = g + 4 * r;
        yout[o * 262144 + (y0 + py) * 512 + x0 + px] = po[r];
    }
}

extern "C" void kernel_launch(void* const* d_in, const int* in_sizes, int n_in,
                              void* d_out, int out_size, void* d_ws, size_t ws_size,
                              hipStream_t stream) {
    const float* x      = (const float*)d_in[0];
    const float* qkv_w  = (const float*)d_in[1];
    const float* qkv_b  = (const float*)d_in[2];
    const float* dw_w   = (const float*)d_in[3];
    const float* dw_b   = (const float*)d_in[4];
    const float* proj_w = (const float*)d_in[5];
    const float* proj_b = (const float*)d_in[6];
    const float* temp   = (const float*)d_in[7];
    const float* relb   = (const float*)d_in[8];
    float* o = (float*)d_out;
    hipLaunchKernelGGL(fused_win_attn, dim3(4096), dim3(256), 0, stream,
                       x, qkv_w, qkv_b, dw_w, dw_b, proj_w, proj_b, temp, relb, o);
}

// Round 3
// 654.770 us; speedup vs baseline: 3.1340x; 3.1340x over previous
//
#include <hip/hip_runtime.h>

typedef short short8 __attribute__((ext_vector_type(8)));
typedef float float4v __attribute__((ext_vector_type(4)));

__device__ __forceinline__ unsigned short f2bf(float f) {
    unsigned int u = __float_as_uint(f);
    u += 0x7fffu + ((u >> 16) & 1u);   // RNE
    return (unsigned short)(u >> 16);
}
__device__ __forceinline__ float bfs(const unsigned short* p) {
    return __uint_as_float(((unsigned int)*p) << 16);
}
__device__ __forceinline__ float4v mfma16(short8 a, short8 b, float4v c) {
    return __builtin_amdgcn_mfma_f32_16x16x32_bf16(a, b, c, 0, 0, 0);
}

// ---- prep: pack qkv_w (288x96) and proj_w (96x96) fp32 -> bf16 in
// MFMA A-fragment-linear order. apack[(tile*3+f)*64 + lane][j] =
// W[tile*16 + (lane&15)][f*32 + (lane>>4)*8 + j]
__global__ void prep_pack(const float* __restrict__ qkv_w,
                          const float* __restrict__ proj_w,
                          short* __restrict__ apq, short* __restrict__ app) {
    const int i = blockIdx.x * 256 + threadIdx.x;
    if (i < 3456) {                          // 18 tiles * 3 frags * 64 lanes
        const int rem = i % 192, f = rem / 64, lane = rem % 64;
        const int m = (i / 192) * 16 + (lane & 15);
        const int kb = f * 32 + ((lane >> 4) & 3) * 8;
        const float* s = qkv_w + m * 96 + kb;
        short8 o;
        #pragma unroll
        for (int j = 0; j < 8; ++j) o[j] = (short)f2bf(s[j]);
        *(short8*)(apq + i * 8) = o;
    } else if (i < 4608) {                   // 6 tiles * 3 frags * 64 lanes
        const int i2 = i - 3456;
        const int rem = i2 % 192, f = rem / 64, lane = rem % 64;
        const int m = (i2 / 192) * 16 + (lane & 15);
        const int kb = f * 32 + ((lane >> 4) & 3) * 8;
        const float* s = proj_w + m * 96 + kb;
        short8 o;
        #pragma unroll
        for (int j = 0; j < 8; ++j) o[j] = (short)f2bf(s[j]);
        *(short8*)(app + i2 * 8) = o;
    }
}

// One block per 8x8 window, 256 threads = 4 waves. MFMA everywhere matmul-shaped.
__global__ __launch_bounds__(256, 2)
void fused_win_attn(const float* __restrict__ x,
                    const short* __restrict__ apq,   // packed qkv_w bf16
                    const float* __restrict__ qkv_b,
                    const float* __restrict__ dw_w,
                    const float* __restrict__ dw_b,
                    const short* __restrict__ app,   // packed proj_w bf16
                    const float* __restrict__ proj_b,
                    const float* __restrict__ temperature,
                    const float* __restrict__ rel_bias,
                    float* __restrict__ yout)
{
    __shared__ __align__(16) unsigned char smem[60688];
    unsigned short* sxT   = (unsigned short*)smem;            // [64][104] x^T bf16
    unsigned short* soutT = (unsigned short*)(smem + 13312);  // [64][104] pre-proj^T
    unsigned short* sbias = (unsigned short*)(smem + 26624);  // [225*6] rel bias bf16
    unsigned short* sqkv  = (unsigned short*)(smem + 29328);  // [48][72] post-dw (q,k normed)
    unsigned short* raw   = (unsigned short*)(smem + 36240);  // [48][65] pre-dw   (union A)
    unsigned short* sST   = (unsigned short*)(smem + 36240);  // [64][72] S^T      (union A)
    unsigned short* qnT   = (unsigned short*)(smem + 45456);  // [64][24]
    unsigned short* knT   = (unsigned short*)(smem + 48528);  // [64][24]
    unsigned short* vT    = (unsigned short*)(smem + 51600);  // [64][24]
    unsigned short* stmp  = (unsigned short*)(smem + 54672);  // [16][72] attn_ch@v
    unsigned short* ach   = (unsigned short*)(smem + 56976);  // [16][24] attn_ch
    float*          sdw   = (float*)(smem + 57744);           // [48][10] dw taps+bias
    float*          sred  = (float*)(smem + 59664);           // [4][64] softmax partials

    const int tid  = threadIdx.x;
    const int lane = tid & 63;
    const int g    = tid >> 6;          // wave 0..3
    const int quad = lane >> 4;         // 0..3
    const int l15  = lane & 15;
    const int wi   = blockIdx.x;
    const int y0   = (wi >> 6) << 3;
    const int x0   = (wi & 63) << 3;
    const int py   = lane >> 3, px = lane & 7;

    // ---- stage x window transposed [px][ch] bf16; rel_bias bf16 ----
    for (int r = tid; r < 1536; r += 256) {
        const int c = r >> 4, q4 = r & 15, p0 = q4 * 4;
        float4 v = *(const float4*)(x + c * 262144 + (y0 + (p0 >> 3)) * 512 + x0 + (p0 & 7));
        sxT[(p0 + 0) * 104 + c] = f2bf(v.x);
        sxT[(p0 + 1) * 104 + c] = f2bf(v.y);
        sxT[(p0 + 2) * 104 + c] = f2bf(v.z);
        sxT[(p0 + 3) * 104 + c] = f2bf(v.w);
    }
    for (int r = tid; r < 1350; r += 256) sbias[r] = f2bf(rel_bias[r]);
    __syncthreads();

    for (int h = 0; h < 6; ++h) {
        // ---- P1: stage dw taps; qkv GEMM via MFMA (wave g owns px-tile g) ----
        for (int r = tid; r < 480; r += 256) {
            const int j = r / 10, t = r % 10;
            const int O = (j >> 4) * 96 + h * 16 + (j & 15);
            sdw[r] = (t < 9) ? dw_w[O * 9 + t] : dw_b[O];
        }
        {
            short8 bf[3];
            #pragma unroll
            for (int f = 0; f < 3; ++f)
                bf[f] = *(const short8*)(sxT + (g * 16 + l15) * 104 + f * 32 + quad * 8);
            #pragma unroll
            for (int t = 0; t < 3; ++t) {
                float4v acc = {0.f, 0.f, 0.f, 0.f};
                #pragma unroll
                for (int f = 0; f < 3; ++f) {
                    short8 af = *(const short8*)(apq + (((t * 6 + h) * 3 + f) * 64 + lane) * 8);
                    acc = mfma16(af, bf[f], acc);
                }
                #pragma unroll
                for (int reg = 0; reg < 4; ++reg) {
                    const int rr = quad * 4 + reg;
                    raw[(t * 16 + rr) * 65 + g * 16 + l15] =
                        f2bf(acc[reg] + qkv_b[t * 96 + h * 16 + rr]);
                }
            }
        }
        __syncthreads();   // B1

        // ---- P2: depthwise 3x3 (shfl neighbors) + L2 norm + transposes ----
        #pragma unroll
        for (int r = 0; r < 12; ++r) {
            const int j = g + 4 * r;                 // 0..47, wave-private
            const float v = bfs(raw + j * 65 + lane);
            const float* w = sdw + j * 10;
            float a = w[9];
            #pragma unroll
            for (int di = 0; di < 3; ++di) {
                #pragma unroll
                for (int dj = 0; dj < 3; ++dj) {
                    const int off = (di - 1) * 8 + (dj - 1);
                    const float nb = (off == 0) ? v : __shfl(v, lane + off, 64);
                    const bool ok = ((unsigned)(py + di - 1) < 8u) & ((unsigned)(px + dj - 1) < 8u);
                    a = fmaf(w[di * 3 + dj], ok ? nb : 0.f, a);
                }
            }
            if (j < 32) {
                float ss = a * a;
                #pragma unroll
                for (int m = 1; m < 64; m <<= 1) ss += __shfl_xor(ss, m, 64);
                const float nv = a * (1.f / fmaxf(sqrtf(ss), 1e-12f));
                const unsigned short b = f2bf(nv);
                sqkv[j * 72 + lane] = b;
                if (j < 16) qnT[lane * 24 + j] = b;
                else        knT[lane * 24 + (j - 16)] = b;
            } else {
                vT[lane * 24 + (j - 32)] = f2bf(a);
            }
        }
        __syncthreads();   // B2

        // ---- P3: spatial logits S^T = knT @ qn (K=16 pad 32), exp, partial sums;
        //          wave 0 additionally: channel attention + softmax ----
        float ex[16];
        {
            short8 ak = {0,0,0,0,0,0,0,0};
            if (lane < 32) ak = *(const short8*)(knT + (g * 16 + l15) * 24 + quad * 8);
            #pragma unroll
            for (int nt = 0; nt < 4; ++nt) {
                short8 bq = {0,0,0,0,0,0,0,0};
                if (lane < 32) bq = *(const short8*)(qnT + (nt * 16 + l15) * 24 + quad * 8);
                float4v cs = {0.f, 0.f, 0.f, 0.f};
                cs = mfma16(ak, bq, cs);
                float ps = 0.f;
                #pragma unroll
                for (int reg = 0; reg < 4; ++reg) {
                    const int m = g * 16 + quad * 4 + reg;       // S^T row
                    const int n = nt * 16 + l15;                 // S^T col
                    const int idx = ((n >> 3) - (m >> 3) + 7) * 15 + ((n & 7) - (m & 7) + 7);
                    const float e = __expf(cs[reg] + bfs(sbias + idx * 6 + h));
                    ex[nt * 4 + reg] = e;
                    ps += e;
                }
                ps += __shfl_xor(ps, 16, 64);
                ps += __shfl_xor(ps, 32, 64);
                if (lane < 16) sred[g * 64 + nt * 16 + lane] = ps;
            }
        }
        if (g == 0) {      // channel attention (16x16, K=64)
            short8 a0 = *(const short8*)(sqkv + l15 * 72 + quad * 8);
            short8 a1 = *(const short8*)(sqkv + l15 * 72 + 32 + quad * 8);
            short8 b0 = *(const short8*)(sqkv + (16 + l15) * 72 + quad * 8);
            short8 b1 = *(const short8*)(sqkv + (16 + l15) * 72 + 32 + quad * 8);
            float4v cc = {0.f, 0.f, 0.f, 0.f};
            cc = mfma16(a0, b0, cc);
            cc = mfma16(a1, b1, cc);
            const float tp = temperature[h];
            #pragma unroll
            for (int reg = 0; reg < 4; ++reg) {
                const float e = __expf(cc[reg] * tp);
                float se = e;
                #pragma unroll
                for (int m = 1; m < 16; m <<= 1) se += __shfl_xor(se, m, 64);
                ach[(quad * 4 + reg) * 24 + l15] = f2bf(e / se);
            }
        }
        __syncthreads();   // B3

        // ---- P4: normalize S^T -> sST bf16; apply-ch: tmp = attn_ch @ v ----
        #pragma unroll
        for (int nt = 0; nt < 4; ++nt) {
            const int n = nt * 16 + l15;
            const float inv = 1.f / (sred[n] + sred[64 + n] + sred[128 + n] + sred[192 + n]);
            #pragma unroll
            for (int reg = 0; reg < 4; ++reg)
                sST[(g * 16 + quad * 4 + reg) * 72 + n] = f2bf(ex[nt * 4 + reg] * inv);
        }
        {
            short8 af = {0,0,0,0,0,0,0,0}, bf = {0,0,0,0,0,0,0,0};
            if (lane < 32) {
                af = *(const short8*)(ach + l15 * 24 + quad * 8);
                bf = *(const short8*)(vT + (g * 16 + l15) * 24 + quad * 8);
            }
            float4v ct = {0.f, 0.f, 0.f, 0.f};
            ct = mfma16(af, bf, ct);
            #pragma unroll
            for (int reg = 0; reg < 4; ++reg)
                stmp[(quad * 4 + reg) * 72 + g * 16 + l15] = f2bf(ct[reg]);
        }
        __syncthreads();   // B4

        // ---- P5: out_h = tmp @ S (B = S^T rows), accumulate into soutT ----
        {
            short8 a0 = *(const short8*)(stmp + l15 * 72 + quad * 8);
            short8 a1 = *(const short8*)(stmp + l15 * 72 + 32 + quad * 8);
            short8 b0 = *(const short8*)(sST + (g * 16 + l15) * 72 + quad * 8);
            short8 b1 = *(const short8*)(sST + (g * 16 + l15) * 72 + 32 + quad * 8);
            float4v co = {0.f, 0.f, 0.f, 0.f};
            co = mfma16(a0, b0, co);
            co = mfma16(a1, b1, co);
            #pragma unroll
            for (int reg = 0; reg < 4; ++reg)
                soutT[(g * 16 + l15) * 104 + h * 16 + quad * 4 + reg] = f2bf(co[reg]);
        }
        __syncthreads();   // B5 (protects raw/sST union for next head)
    }

    // ---- proj GEMM (96x64, K=96) + bias + window-reverse store ----
    {
        short8 pb[3];
        #pragma unroll
        for (int f = 0; f < 3; ++f)
            pb[f] = *(const short8*)(soutT + (g * 16 + l15) * 104 + f * 32 + quad * 8);
        const int p = g * 16 + l15;
        float* outbase = yout + (y0 + (p >> 3)) * 512 + x0 + (p & 7);
        #pragma unroll
        for (int mt = 0; mt < 6; ++mt) {
            float4v acc = {0.f, 0.f, 0.f, 0.f};
            #pragma unroll
            for (int f = 0; f < 3; ++f) {
                short8 af = *(const short8*)(app + ((mt * 3 + f) * 64 + lane) * 8);
                acc = mfma16(af, pb[f], acc);
            }
            #pragma unroll
            for (int reg = 0; reg < 4; ++reg) {
                const int o = mt * 16 + quad * 4 + reg;
                outbase[o * 262144] = acc[reg] + proj_b[o];
            }
        }
    }
}

extern "C" void kernel_launch(void* const* d_in, const int* in_sizes, int n_in,
                              void* d_out, int out_size, void* d_ws, size_t ws_size,
                              hipStream_t stream) {
    const float* x      = (const float*)d_in[0];
    const float* qkv_w  = (const float*)d_in[1];
    const float* qkv_b  = (const float*)d_in[2];
    const float* dw_w   = (const float*)d_in[3];
    const float* dw_b   = (const float*)d_in[4];
    const float* proj_w = (const float*)d_in[5];
    const float* proj_b = (const float*)d_in[6];
    const float* temp   = (const float*)d_in[7];
    const float* relb   = (const float*)d_in[8];
    float* o = (float*)d_out;

    short* apq = (short*)d_ws;              // 27648 bf16
    short* app = apq + 27648;               // 9216 bf16

    hipLaunchKernelGGL(prep_pack, dim3(18), dim3(256), 0, stream, qkv_w, proj_w, apq, app);
    hipLaunchKernelGGL(fused_win_attn, dim3(4096), dim3(256), 0, stream,
                       x, apq, qkv_b, dw_w, dw_b, app, proj_b, temp, relb, o);
}